// Round 2
// baseline (222.055 us; speedup 1.0000x reference)
//
#include <hip/hip_runtime.h>
#include <stdint.h>

#define C_CH 192
#define HW   4096
#define NB   16
#define NO   5

typedef __attribute__((ext_vector_type(8)))  short short8;
typedef __attribute__((ext_vector_type(16))) float floatx16;

__device__ __forceinline__ unsigned short f2bf(float f) {
    unsigned int u = __float_as_uint(f);
    unsigned int r = (u + 0x7fffu + ((u >> 16) & 1u)) >> 16;  // RNE truncate to bf16
    return (unsigned short)r;
}

// shift fragment toward lower index: out[j] = {ex, f[0..6]}   (dx = -1)
__device__ __forceinline__ short8 shift_m(short8 f, unsigned short ex) {
    uint4 v = *(uint4*)&f; uint4 w;
    w.x = (unsigned)ex   | (v.x << 16);
    w.y = (v.x >> 16)    | (v.y << 16);
    w.z = (v.y >> 16)    | (v.z << 16);
    w.w = (v.z >> 16)    | (v.w << 16);
    return *(short8*)&w;
}
// shift toward higher index: out[j] = {f[1..7], ex}   (dx = +1)
__device__ __forceinline__ short8 shift_p(short8 f, unsigned short ex) {
    uint4 v = *(uint4*)&f; uint4 w;
    w.x = (v.x >> 16) | (v.y << 16);
    w.y = (v.y >> 16) | (v.z << 16);
    w.z = (v.z >> 16) | (v.w << 16);
    w.w = (v.w >> 16) | ((unsigned)ex << 16);
    return *(short8*)&w;
}

// ---------------- Kernel 1: fp32 -> bf16 (+ zero norm accumulators) ----------------
__global__ __launch_bounds__(256) void convert_kernel(const float* __restrict__ x,
                                                      unsigned short* __restrict__ xb,
                                                      float* __restrict__ norms,
                                                      int n8) {
    if (blockIdx.x == 0 && threadIdx.x < NB * NO) norms[threadIdx.x] = 0.0f;
    int i = blockIdx.x * 256 + threadIdx.x;
    if (i >= n8) return;
    const float4* p = (const float4*)(x) + (size_t)i * 2;
    float4 v0 = p[0], v1 = p[1];
    ushort4 o0, o1;
    o0.x = f2bf(v0.x); o0.y = f2bf(v0.y); o0.z = f2bf(v0.z); o0.w = f2bf(v0.w);
    o1.x = f2bf(v1.x); o1.y = f2bf(v1.y); o1.z = f2bf(v1.z); o1.w = f2bf(v1.w);
    ushort4* q = (ushort4*)(xb) + (size_t)i * 2;
    q[0] = o0; q[1] = o1;
}

// ---------------- Kernel 2: fused 5-offset Gram, direct-from-global MFMA ----------------
// grid = 576 = 16 batches x 36 (32x32) (c,d)-tiles. 4 waves split K 4-way (16 h-rows each).
// No LDS in main loop: per-lane 16B fragment loads (channel = lane&31, k-octet = lane>>5),
// dx shifts via register funnel, dy via rolled previous-row fragment (v(h) = u(h-1)).
__global__ __launch_bounds__(256) void cofe_gemm(const unsigned short* __restrict__ xb,
                                                 float* __restrict__ out,
                                                 float* __restrict__ norms) {
    int blk = blockIdx.x;
    // XCD swizzle: 576 = 8*72 -> 2 batches per XCD (3 MB bf16, L2-resident)
    int work = (blk & 7) * 72 + (blk >> 3);
    int b = work / 36;
    int t = work % 36;
    int c0 = (t / 6) * 32, d0 = (t % 6) * 32;

    int wv   = threadIdx.x >> 6;
    int lane = threadIdx.x & 63;
    int lr   = lane & 31;
    int lo   = lane >> 5;
    int lo8  = lo * 8;

    const unsigned short* Arow = xb + ((size_t)(b * C_CH + c0 + lr)) * HW;  // center, m = channel
    const unsigned short* Brow = xb + ((size_t)(b * C_CH + d0 + lr)) * HW;  // side,   n = channel

    floatx16 acc[5];
    #pragma unroll
    for (int o = 0; o < 5; ++o)
        #pragma unroll
        for (int e = 0; e < 16; ++e)
            acc[o][e] = 0.0f;

    int h0 = wv * 16;

    for (int k0 = 0; k0 < 64; k0 += 16) {
        int e0 = k0 + lo8;                       // element offset within 64-wide row
        int em = e0 ? e0 - 1 : 0;                // clamp(w-1)
        int ep = (e0 + 8 < 64) ? e0 + 8 : 63;    // clamp(w+8)
        int hm = h0 ? h0 - 1 : 0;                // clamp(h-1) (only wave 0 clamps)

        // v = fragment of row h-1 (rolled)
        short8 vprev         = *(const short8*)(Brow + hm * 64 + e0);
        unsigned short exm_p = Brow[hm * 64 + em];
        unsigned short exp_p = Brow[hm * 64 + ep];
        // current row h0
        short8 a_c           = *(const short8*)(Arow + h0 * 64 + e0);
        short8 u_c           = *(const short8*)(Brow + h0 * 64 + e0);
        unsigned short exm_c = Brow[h0 * 64 + em];
        unsigned short exp_c = Brow[h0 * 64 + ep];

        #pragma unroll 4
        for (int hi = 0; hi < 16; ++hi) {
            int h  = h0 + hi;
            int hn = (hi < 15) ? h + 1 : h;      // dummy reload on last iter (stays in range)
            // prefetch next row while computing current
            short8 a_n           = *(const short8*)(Arow + hn * 64 + e0);
            short8 u_n           = *(const short8*)(Brow + hn * 64 + e0);
            unsigned short exm_n = Brow[hn * 64 + em];
            unsigned short exp_n = Brow[hn * 64 + ep];

            // OFFSETS = [(-1,-1), (-1,0), (-1,1), (0,-1), (0,0)]
            short8 b0 = shift_m(vprev, exm_p);   // row h-1, dx=-1
            short8 b2 = shift_p(vprev, exp_p);   // row h-1, dx=+1
            short8 b3 = shift_m(u_c,   exm_c);   // row h,   dx=-1
            acc[0] = __builtin_amdgcn_mfma_f32_32x32x16_bf16(a_c, b0,    acc[0], 0, 0, 0);
            acc[1] = __builtin_amdgcn_mfma_f32_32x32x16_bf16(a_c, vprev, acc[1], 0, 0, 0);
            acc[2] = __builtin_amdgcn_mfma_f32_32x32x16_bf16(a_c, b2,    acc[2], 0, 0, 0);
            acc[3] = __builtin_amdgcn_mfma_f32_32x32x16_bf16(a_c, b3,    acc[3], 0, 0, 0);
            acc[4] = __builtin_amdgcn_mfma_f32_32x32x16_bf16(a_c, u_c,   acc[4], 0, 0, 0);

            vprev = u_c; exm_p = exm_c; exp_p = exp_c;
            a_c = a_n; u_c = u_n; exm_c = exm_n; exp_c = exp_n;
        }
    }

    // ---- epilogue: LDS-reduce 4 split-K partials, store, fused sumsq atomics ----
    __shared__ float red[4096];   // 16 KB
    float4* red4 = (float4*)red;
    size_t obase = (size_t)b * NO * (C_CH * C_CH);
    int tt = threadIdx.x;

    for (int o = 0; o < 5; ++o) {
        __syncthreads();   // WAR: red reused across offsets
        #pragma unroll
        for (int reg = 0; reg < 16; ++reg) {
            int row = (reg & 3) + 8 * (reg >> 2) + 4 * lo;  // C/D layout (m74/m101)
            red[wv * 1024 + row * 32 + lr] = acc[o][reg];
        }
        __syncthreads();
        float4 s  = red4[tt];
        float4 s1 = red4[256 + tt];
        float4 s2 = red4[512 + tt];
        float4 s3 = red4[768 + tt];
        s.x += s1.x + s2.x + s3.x;
        s.y += s1.y + s2.y + s3.y;
        s.z += s1.z + s2.z + s3.z;
        s.w += s1.w + s2.w + s3.w;
        int row = tt >> 3;
        int col = (tt & 7) * 4;
        float* op = out + obase + (size_t)o * (C_CH * C_CH) + (size_t)(c0 + row) * C_CH + d0 + col;
        *(float4*)op = s;

        float ss = s.x * s.x + s.y * s.y + s.z * s.z + s.w * s.w;
        #pragma unroll
        for (int off = 32; off; off >>= 1) ss += __shfl_down(ss, off, 64);
        if (lane == 0) atomicAdd(&norms[b * NO + o], ss);
    }
}

// ---------------- Kernel 3: scale by 1/norm ----------------
__global__ __launch_bounds__(256) void scale_kernel(float* __restrict__ out,
                                                    const float* __restrict__ norms) {
    int g  = blockIdx.x * 256 + threadIdx.x;     // float4 index, 737280 total
    int bo = blockIdx.x / 36;                    // 9216 float4 per (b,o); 36 blocks per bo
    float s = norms[bo];
    float inv = 1.0f / fmaxf(sqrtf(s), 1e-12f);
    float4 v = ((const float4*)out)[g];
    v.x *= inv; v.y *= inv; v.z *= inv; v.w *= inv;
    ((float4*)out)[g] = v;
}

extern "C" void kernel_launch(void* const* d_in, const int* in_sizes, int n_in,
                              void* d_out, int out_size, void* d_ws, size_t ws_size,
                              hipStream_t stream) {
    const float* x = (const float*)d_in[0];
    float* out = (float*)d_out;
    float* norms = (float*)d_ws;                                   // 80 floats
    unsigned short* xb = (unsigned short*)((char*)d_ws + 512);     // 25,165,824 B bf16

    int total = NB * C_CH * HW;   // 12,582,912
    int n8 = total / 8;           // 1,572,864 -> 6144 blocks

    convert_kernel<<<n8 / 256, 256, 0, stream>>>(x, xb, norms, n8);
    cofe_gemm<<<576, 256, 0, stream>>>(xb, out, norms);
    scale_kernel<<<2880, 256, 0, stream>>>(out, norms);
}

// Round 3
// 184.016 us; speedup vs baseline: 1.2067x; 1.2067x over previous
//
#include <hip/hip_runtime.h>
#include <stdint.h>

#define C_CH 192
#define HW   4096
#define NB   16
#define NO   5

typedef __attribute__((ext_vector_type(8)))  short short8;
typedef __attribute__((ext_vector_type(16))) float floatx16;

__device__ __forceinline__ unsigned short f2bf(float f) {
    unsigned int u = __float_as_uint(f);
    unsigned int r = (u + 0x7fffu + ((u >> 16) & 1u)) >> 16;  // RNE to bf16
    return (unsigned short)r;
}

__device__ __forceinline__ uint4 s8u4(short8 f) { return *(uint4*)&f; }

// shift fragment toward lower index: out[j] = {ex, f[0..6]}   (dx = -1)
__device__ __forceinline__ short8 shift_m(short8 f, unsigned short ex) {
    uint4 v = *(uint4*)&f; uint4 w;
    w.x = (unsigned)ex   | (v.x << 16);
    w.y = (v.x >> 16)    | (v.y << 16);
    w.z = (v.y >> 16)    | (v.z << 16);
    w.w = (v.z >> 16)    | (v.w << 16);
    return *(short8*)&w;
}
// shift toward higher index: out[j] = {f[1..7], ex}   (dx = +1)
__device__ __forceinline__ short8 shift_p(short8 f, unsigned short ex) {
    uint4 v = *(uint4*)&f; uint4 w;
    w.x = (v.x >> 16) | (v.y << 16);
    w.y = (v.y >> 16) | (v.z << 16);
    w.z = (v.z >> 16) | (v.w << 16);
    w.w = (v.w >> 16) | ((unsigned)ex << 16);
    return *(short8*)&w;
}

// Build shifted variants of the 16-elem k-step fragment held as Uarr[S] across the
// lo=0/lo=1 half-waves. Edge elements come from the partner lane (lane^32) via shfl,
// with w=0 / w=63 clamps at S==0 (lo=0) and S==3 (lo=1).
#define MAKE_SHIFT(Uarr, S, Um, Up)                                              \
    do {                                                                         \
        uint4 _u0 = s8u4(Uarr[(S) > 0 ? (S) - 1 : 0]);                           \
        uint4 _u1 = s8u4(Uarr[S]);                                               \
        uint4 _u2 = s8u4(Uarr[(S) < 3 ? (S) + 1 : 3]);                           \
        unsigned _sm = lo ? _u0.w : _u1.w;                                       \
        unsigned _sp = lo ? _u1.x : _u2.x;                                       \
        unsigned _rm = (unsigned)__shfl_xor((int)_sm, 32, 64);                   \
        unsigned _rp = (unsigned)__shfl_xor((int)_sp, 32, 64);                   \
        unsigned short _exm = (unsigned short)(_rm >> 16);                       \
        if ((S) == 0) _exm = lo ? _exm : (unsigned short)(_u1.x & 0xffffu);      \
        unsigned short _exp = (unsigned short)(_rp & 0xffffu);                   \
        if ((S) == 3) _exp = lo ? (unsigned short)(_u1.w >> 16) : _exp;          \
        Um = shift_m(Uarr[S], _exm);                                             \
        Up = shift_p(Uarr[S], _exp);                                             \
    } while (0)

// ---------------- Kernel 1: fp32 -> bf16, fragment-tiled layout ----------------
// xb short index: ((b*6+cb)*512 + q)*256 + c'*8 + j   (cb = ch>>5, c' = ch&31, q = k>>3)
// Thread t writes output short8 #t (perfectly coalesced); reads 32B of one channel row
// (q,q+1 thread pairs share each 64B input line -> full line utilization).
__global__ __launch_bounds__(256) void convert_kernel(const float* __restrict__ x,
                                                      unsigned short* __restrict__ xb,
                                                      float* __restrict__ norms) {
    if (blockIdx.x == 0 && threadIdx.x < NB * NO) norms[threadIdx.x] = 0.0f;
    int t   = blockIdx.x * 256 + threadIdx.x;   // 1,572,864 threads exactly
    int cq  = t >> 5;                           // (b*6+cb)*512 + q
    int cp  = t & 31;
    int bcb = cq >> 9;
    int q   = cq & 511;
    int b   = bcb / 6;
    int ch  = (bcb - b * 6) * 32 + cp;
    size_t fi = (size_t)(b * C_CH + ch) * HW + q * 8;
    const float4* p = (const float4*)(x + fi);
    float4 v0 = p[0], v1 = p[1];
    ushort4 o0, o1;
    o0.x = f2bf(v0.x); o0.y = f2bf(v0.y); o0.z = f2bf(v0.z); o0.w = f2bf(v0.w);
    o1.x = f2bf(v1.x); o1.y = f2bf(v1.y); o1.z = f2bf(v1.z); o1.w = f2bf(v1.w);
    ushort4* dst = (ushort4*)xb + (size_t)t * 2;
    dst[0] = o0; dst[1] = o1;
}

// ---------------- Kernel 2: fused 5-offset Gram ----------------
// grid 576 = 16 b x 36 (32x32)-tiles; 4 waves split K by h-rows (16 rows each).
// dy=-1 terms re-indexed: sum_g A[g+1]*B[g]  (+ A[0]*B[0] boundary in wave 0),
// so only the current B row needs shift edges (2 shfl_xor per k-step, no LDS,
// no scalar loads). Full-row register prefetch: A rows g,g+1,g+2; B rows g,g+1.
__global__ __launch_bounds__(256) void cofe_gemm(const unsigned short* __restrict__ xb,
                                                 float* __restrict__ out,
                                                 float* __restrict__ norms) {
    int blk  = blockIdx.x;
    int work = (blk & 7) * 72 + (blk >> 3);     // XCD swizzle: 2 batches per XCD
    int b = work / 36;
    int t = work % 36;
    int cbA = t / 6, cbB = t % 6;
    int c0 = cbA * 32, d0 = cbB * 32;

    int wv   = threadIdx.x >> 6;
    int lane = threadIdx.x & 63;
    int lr   = lane & 31;
    int lo   = lane >> 5;
    int laneoff = lo * 32 + lr;                 // short8 units

    const short8* A8 = (const short8*)xb + (size_t)(b * 6 + cbA) * 16384;
    const short8* B8 = (const short8*)xb + (size_t)(b * 6 + cbB) * 16384;

    floatx16 acc[5];
    #pragma unroll
    for (int o = 0; o < 5; ++o)
        #pragma unroll
        for (int e = 0; e < 16; ++e)
            acc[o][e] = 0.0f;

    int h0 = wv * 16;

    short8 U[2][4];   // B rows: ping-pong
    short8 A[3][4];   // A rows: rotate (g, g+1, g+2)

    #pragma unroll
    for (int s = 0; s < 4; ++s) {
        U[0][s] = B8[(8 * h0 + 2 * s) * 32 + laneoff];
        A[0][s] = A8[(8 * h0 + 2 * s) * 32 + laneoff];
        A[1][s] = A8[(8 * (h0 + 1) + 2 * s) * 32 + laneoff];
    }

    // h = 0 boundary: dy=-1 offsets pair center row 0 with clamped side row 0
    if (h0 == 0) {
        #pragma unroll
        for (int s = 0; s < 4; ++s) {
            short8 Um, Up;
            MAKE_SHIFT(U[0], s, Um, Up);
            acc[0] = __builtin_amdgcn_mfma_f32_32x32x16_bf16(A[0][s], Um,      acc[0], 0, 0, 0);
            acc[1] = __builtin_amdgcn_mfma_f32_32x32x16_bf16(A[0][s], U[0][s], acc[1], 0, 0, 0);
            acc[2] = __builtin_amdgcn_mfma_f32_32x32x16_bf16(A[0][s], Up,      acc[2], 0, 0, 0);
        }
    }

    #pragma unroll
    for (int r = 0; r < 16; ++r) {
        int g  = h0 + r;
        const int cu = r & 1, nx = (r + 1) & 1;
        const int ia = r % 3, ib = (r + 1) % 3, ic = (r + 2) % 3;
        int ga = (g + 2 < 64) ? g + 2 : 63;     // A prefetch row (clamped dummy at tail)
        int gu = (g + 1 < 64) ? g + 1 : 63;     // B prefetch row
        #pragma unroll
        for (int s = 0; s < 4; ++s) {
            A[ic][s] = A8[(8 * ga + 2 * s) * 32 + laneoff];
            U[nx][s] = B8[(8 * gu + 2 * s) * 32 + laneoff];

            short8 Um, Up;
            MAKE_SHIFT(U[cu], s, Um, Up);

            // OFFSETS: 0:(-1,-1) 1:(-1,0) 2:(-1,1) 3:(0,-1) 4:(0,0)
            acc[4] = __builtin_amdgcn_mfma_f32_32x32x16_bf16(A[ia][s], U[cu][s], acc[4], 0, 0, 0);
            acc[3] = __builtin_amdgcn_mfma_f32_32x32x16_bf16(A[ia][s], Um,       acc[3], 0, 0, 0);
            if (r + 1 < 16 || g < 63) {         // dy=-1 sum runs g = 0..62
                acc[1] = __builtin_amdgcn_mfma_f32_32x32x16_bf16(A[ib][s], U[cu][s], acc[1], 0, 0, 0);
                acc[0] = __builtin_amdgcn_mfma_f32_32x32x16_bf16(A[ib][s], Um,       acc[0], 0, 0, 0);
                acc[2] = __builtin_amdgcn_mfma_f32_32x32x16_bf16(A[ib][s], Up,       acc[2], 0, 0, 0);
            }
        }
    }

    // ---- epilogue: LDS-reduce 4 split-K partials, store, fused sumsq atomics ----
    __shared__ float red[4096];   // 16 KB
    float4* red4 = (float4*)red;
    size_t obase = (size_t)b * NO * (C_CH * C_CH);
    int tt = threadIdx.x;

    for (int o = 0; o < 5; ++o) {
        __syncthreads();
        #pragma unroll
        for (int reg = 0; reg < 16; ++reg) {
            int row = (reg & 3) + 8 * (reg >> 2) + 4 * lo;  // C/D layout (m74/m101)
            red[wv * 1024 + row * 32 + lr] = acc[o][reg];
        }
        __syncthreads();
        float4 s  = red4[tt];
        float4 s1 = red4[256 + tt];
        float4 s2 = red4[512 + tt];
        float4 s3 = red4[768 + tt];
        s.x += s1.x + s2.x + s3.x;
        s.y += s1.y + s2.y + s3.y;
        s.z += s1.z + s2.z + s3.z;
        s.w += s1.w + s2.w + s3.w;
        int row = tt >> 3;
        int col = (tt & 7) * 4;
        float* op = out + obase + (size_t)o * (C_CH * C_CH) + (size_t)(c0 + row) * C_CH + d0 + col;
        *(float4*)op = s;

        float ss = s.x * s.x + s.y * s.y + s.z * s.z + s.w * s.w;
        #pragma unroll
        for (int off = 32; off; off >>= 1) ss += __shfl_down(ss, off, 64);
        if (lane == 0) atomicAdd(&norms[b * NO + o], ss);
    }
}

// ---------------- Kernel 3: scale by 1/norm ----------------
__global__ __launch_bounds__(256) void scale_kernel(float* __restrict__ out,
                                                    const float* __restrict__ norms) {
    int g  = blockIdx.x * 256 + threadIdx.x;     // float4 index, 737280 total
    int bo = blockIdx.x / 36;                    // 9216 float4 per (b,o)
    float s = norms[bo];
    float inv = 1.0f / fmaxf(sqrtf(s), 1e-12f);
    float4 v = ((const float4*)out)[g];
    v.x *= inv; v.y *= inv; v.z *= inv; v.w *= inv;
    ((float4*)out)[g] = v;
}

extern "C" void kernel_launch(void* const* d_in, const int* in_sizes, int n_in,
                              void* d_out, int out_size, void* d_ws, size_t ws_size,
                              hipStream_t stream) {
    const float* x = (const float*)d_in[0];
    float* out = (float*)d_out;
    float* norms = (float*)d_ws;                                   // 80 floats
    unsigned short* xb = (unsigned short*)((char*)d_ws + 512);     // 25,165,824 B bf16 tiled

    convert_kernel<<<6144, 256, 0, stream>>>(x, xb, norms);
    cofe_gemm<<<576, 256, 0, stream>>>(xb, out, norms);
    scale_kernel<<<2880, 256, 0, stream>>>(out, norms);
}